// Round 1
// baseline (1671.370 us; speedup 1.0000x reference)
//
#include <hip/hip_runtime.h>

// Problem constants (fixed by setup_inputs)
#define BB 2
#define TT 2048
#define DD 1024
#define HH 16
#define HD 64
#define MM (BB * TT)          // 4096 rows for projections
#define SCALING 0.125f        // hd^-0.5

// ---------------------------------------------------------------------------
// Dense GEMM with bias + scale:  C[M][N] = (A[M][K] @ W[K][N] + bias) * scale
// Tile 128x64, BK=16, 256 threads, 8x4 micro-tile per thread.
// ---------------------------------------------------------------------------
__global__ __launch_bounds__(256)
void gemm_bias_kernel(const float* __restrict__ A, const float* __restrict__ W,
                      const float* __restrict__ bias, float* __restrict__ C,
                      int M, int N, int K, float scale)
{
    constexpr int BM = 128, BN = 64, BK = 16, TM = 8, TN = 4;
    __shared__ float As[BK][BM + 4];   // transposed A tile, +4 pad keeps b128 alignment & banks clean
    __shared__ float Bs[BK][BN];

    const int tid = threadIdx.x;
    const int tx = tid & 15;           // N direction (16 * 4 = 64)
    const int ty = tid >> 4;           // M direction (16 * 8 = 128)
    const int m0 = blockIdx.y * BM;
    const int n0 = blockIdx.x * BN;

    float c[TM][TN];
#pragma unroll
    for (int i = 0; i < TM; ++i)
#pragma unroll
        for (int j = 0; j < TN; ++j) c[i][j] = 0.f;

    const int ar = tid >> 2;           // 0..63  (A-tile row, +64 second half)
    const int ak = (tid & 3) << 2;     // 0,4,8,12
    const int bk = tid >> 4;           // 0..15  (B-tile k row)
    const int bn = (tid & 15) << 2;    // 0..60

    for (int k0 = 0; k0 < K; k0 += BK) {
#pragma unroll
        for (int r = 0; r < BM; r += 64) {
            const float4 a4 = *reinterpret_cast<const float4*>(&A[(size_t)(m0 + ar + r) * K + k0 + ak]);
            As[ak + 0][ar + r] = a4.x;
            As[ak + 1][ar + r] = a4.y;
            As[ak + 2][ar + r] = a4.z;
            As[ak + 3][ar + r] = a4.w;
        }
        *reinterpret_cast<float4*>(&Bs[bk][bn]) =
            *reinterpret_cast<const float4*>(&W[(size_t)(k0 + bk) * N + n0 + bn]);
        __syncthreads();
#pragma unroll
        for (int kk = 0; kk < BK; ++kk) {
            float a_frag[TM], b_frag[TN];
#pragma unroll
            for (int i = 0; i < TM; ++i) a_frag[i] = As[kk][ty * TM + i];
#pragma unroll
            for (int j = 0; j < TN; ++j) b_frag[j] = Bs[kk][tx * TN + j];
#pragma unroll
            for (int i = 0; i < TM; ++i)
#pragma unroll
                for (int j = 0; j < TN; ++j)
                    c[i][j] += a_frag[i] * b_frag[j];
        }
        __syncthreads();
    }

#pragma unroll
    for (int i = 0; i < TM; ++i) {
        const int m = m0 + ty * TM + i;
        float4 o;
        o.x = (c[i][0] + bias[n0 + tx * TN + 0]) * scale;
        o.y = (c[i][1] + bias[n0 + tx * TN + 1]) * scale;
        o.z = (c[i][2] + bias[n0 + tx * TN + 2]) * scale;
        o.w = (c[i][3] + bias[n0 + tx * TN + 3]) * scale;
        *reinterpret_cast<float4*>(&C[(size_t)m * N + n0 + tx * TN]) = o;
    }
}

// ---------------------------------------------------------------------------
// Raw attention scores (per b,h):  S[i][j] = q_bh[i]·k_bh[j] + mask[b,i,j]
// q/k rows live inside [B,T,D] with head offset h*HD, row stride D. K = 64.
// Writes un-normalized scores into the attn_weights output region.
// ---------------------------------------------------------------------------
__global__ __launch_bounds__(256)
void scores_kernel(const float* __restrict__ q, const float* __restrict__ kmat,
                   const float* __restrict__ mask, float* __restrict__ wout)
{
    constexpr int BM = 128, BN = 64, BK = 16, TM = 8, TN = 4;
    const int z = blockIdx.z;              // b*H + h
    const int b = z >> 4, h = z & 15;
    const float* qb = q + (size_t)b * TT * DD + h * HD;
    const float* kb = kmat + (size_t)b * TT * DD + h * HD;
    const float* mb = mask + (size_t)b * TT * TT;
    float* outp = wout + (size_t)z * TT * TT;

    __shared__ float As[BK][BM + 4];   // q^T tile: As[d][i]
    __shared__ float Bs[BK][BN + 4];   // k^T tile: Bs[d][j]

    const int tid = threadIdx.x;
    const int tx = tid & 15;
    const int ty = tid >> 4;
    const int m0 = blockIdx.y * BM;    // query rows
    const int n0 = blockIdx.x * BN;    // key cols

    float c[TM][TN];
#pragma unroll
    for (int i = 0; i < TM; ++i)
#pragma unroll
        for (int j = 0; j < TN; ++j) c[i][j] = 0.f;

    const int ar = tid >> 2;           // 0..63
    const int ad = (tid & 3) << 2;     // 0,4,8,12

    for (int k0 = 0; k0 < HD; k0 += BK) {
#pragma unroll
        for (int r = 0; r < BM; r += 64) {
            const float4 a4 = *reinterpret_cast<const float4*>(&qb[(size_t)(m0 + ar + r) * DD + k0 + ad]);
            As[ad + 0][ar + r] = a4.x;
            As[ad + 1][ar + r] = a4.y;
            As[ad + 2][ar + r] = a4.z;
            As[ad + 3][ar + r] = a4.w;
        }
        {
            const float4 b4 = *reinterpret_cast<const float4*>(&kb[(size_t)(n0 + ar) * DD + k0 + ad]);
            Bs[ad + 0][ar] = b4.x;
            Bs[ad + 1][ar] = b4.y;
            Bs[ad + 2][ar] = b4.z;
            Bs[ad + 3][ar] = b4.w;
        }
        __syncthreads();
#pragma unroll
        for (int kk = 0; kk < BK; ++kk) {
            float a_frag[TM], b_frag[TN];
#pragma unroll
            for (int i = 0; i < TM; ++i) a_frag[i] = As[kk][ty * TM + i];
#pragma unroll
            for (int j = 0; j < TN; ++j) b_frag[j] = Bs[kk][tx * TN + j];
#pragma unroll
            for (int i = 0; i < TM; ++i)
#pragma unroll
                for (int j = 0; j < TN; ++j)
                    c[i][j] += a_frag[i] * b_frag[j];
        }
        __syncthreads();
    }

#pragma unroll
    for (int i = 0; i < TM; ++i) {
        const int m = m0 + ty * TM + i;
        const float4 mk = *reinterpret_cast<const float4*>(&mb[(size_t)m * TT + n0 + tx * TN]);
        float4 o;
        o.x = c[i][0] + mk.x;
        o.y = c[i][1] + mk.y;
        o.z = c[i][2] + mk.z;
        o.w = c[i][3] + mk.w;
        *reinterpret_cast<float4*>(&outp[(size_t)m * TT + n0 + tx * TN]) = o;
    }
}

// ---------------------------------------------------------------------------
// In-place row softmax over 2048-wide rows (65536 rows). 256 threads/row.
// ---------------------------------------------------------------------------
__global__ __launch_bounds__(256)
void softmax_kernel(float* __restrict__ w)
{
    __shared__ float redmax[4];
    __shared__ float redsum[4];
    float* p = w + (size_t)blockIdx.x * TT;
    const int tid = threadIdx.x;

    float4 x0 = reinterpret_cast<const float4*>(p)[tid];
    float4 x1 = reinterpret_cast<const float4*>(p)[tid + 256];

    float m = fmaxf(fmaxf(fmaxf(x0.x, x0.y), fmaxf(x0.z, x0.w)),
                    fmaxf(fmaxf(x1.x, x1.y), fmaxf(x1.z, x1.w)));
#pragma unroll
    for (int off = 32; off; off >>= 1) m = fmaxf(m, __shfl_xor(m, off));
    if ((tid & 63) == 0) redmax[tid >> 6] = m;
    __syncthreads();
    m = fmaxf(fmaxf(redmax[0], redmax[1]), fmaxf(redmax[2], redmax[3]));

    x0.x = __expf(x0.x - m); x0.y = __expf(x0.y - m);
    x0.z = __expf(x0.z - m); x0.w = __expf(x0.w - m);
    x1.x = __expf(x1.x - m); x1.y = __expf(x1.y - m);
    x1.z = __expf(x1.z - m); x1.w = __expf(x1.w - m);

    float s = (x0.x + x0.y + x0.z + x0.w) + (x1.x + x1.y + x1.z + x1.w);
#pragma unroll
    for (int off = 32; off; off >>= 1) s += __shfl_xor(s, off);
    if ((tid & 63) == 0) redsum[tid >> 6] = s;
    __syncthreads();
    s = redsum[0] + redsum[1] + redsum[2] + redsum[3];

    const float inv = 1.0f / s;
    x0.x *= inv; x0.y *= inv; x0.z *= inv; x0.w *= inv;
    x1.x *= inv; x1.y *= inv; x1.z *= inv; x1.w *= inv;
    reinterpret_cast<float4*>(p)[tid] = x0;
    reinterpret_cast<float4*>(p)[tid + 256] = x1;
}

// ---------------------------------------------------------------------------
// PV (per b,h): ctx[i][d] = sum_j W[i][j] * v_bh[j][d]    M=T, N=64, K=T
// ctx written directly in [B,T,D] layout (head offset h*HD) so the output
// projection reads a dense matrix.
// ---------------------------------------------------------------------------
__global__ __launch_bounds__(256)
void pv_kernel(const float* __restrict__ w, const float* __restrict__ v,
               float* __restrict__ ctx)
{
    constexpr int BM = 128, BK = 16, TM = 8, TN = 4;
    const int z = blockIdx.z;
    const int b = z >> 4, h = z & 15;
    const float* wb = w + (size_t)z * TT * TT;
    const float* vb = v + (size_t)b * TT * DD + h * HD;
    float* cb = ctx + (size_t)b * TT * DD + h * HD;

    __shared__ float As[BK][BM + 4];   // weights^T tile: As[j][i]
    __shared__ float Bs[BK][64];       // v tile: Bs[j][d]

    const int tid = threadIdx.x;
    const int tx = tid & 15;
    const int ty = tid >> 4;
    const int m0 = blockIdx.y * BM;

    float c[TM][TN];
#pragma unroll
    for (int i = 0; i < TM; ++i)
#pragma unroll
        for (int j = 0; j < TN; ++j) c[i][j] = 0.f;

    const int ar = tid >> 2;           // 0..63
    const int aj = (tid & 3) << 2;     // 0,4,8,12
    const int bj = tid >> 4;           // 0..15
    const int bd = (tid & 15) << 2;    // 0..60

    for (int k0 = 0; k0 < TT; k0 += BK) {
#pragma unroll
        for (int r = 0; r < BM; r += 64) {
            const float4 a4 = *reinterpret_cast<const float4*>(&wb[(size_t)(m0 + ar + r) * TT + k0 + aj]);
            As[aj + 0][ar + r] = a4.x;
            As[aj + 1][ar + r] = a4.y;
            As[aj + 2][ar + r] = a4.z;
            As[aj + 3][ar + r] = a4.w;
        }
        *reinterpret_cast<float4*>(&Bs[bj][bd]) =
            *reinterpret_cast<const float4*>(&vb[(size_t)(k0 + bj) * DD + bd]);
        __syncthreads();
#pragma unroll
        for (int kk = 0; kk < BK; ++kk) {
            float a_frag[TM], b_frag[TN];
#pragma unroll
            for (int i = 0; i < TM; ++i) a_frag[i] = As[kk][ty * TM + i];
#pragma unroll
            for (int j = 0; j < TN; ++j) b_frag[j] = Bs[kk][tx * TN + j];
#pragma unroll
            for (int i = 0; i < TM; ++i)
#pragma unroll
                for (int j = 0; j < TN; ++j)
                    c[i][j] += a_frag[i] * b_frag[j];
        }
        __syncthreads();
    }

#pragma unroll
    for (int i = 0; i < TM; ++i) {
        const int m = m0 + ty * TM + i;
        float4 o;
        o.x = c[i][0]; o.y = c[i][1]; o.z = c[i][2]; o.w = c[i][3];
        *reinterpret_cast<float4*>(&cb[(size_t)m * DD + tx * TN]) = o;
    }
}

// ---------------------------------------------------------------------------
extern "C" void kernel_launch(void* const* d_in, const int* in_sizes, int n_in,
                              void* d_out, int out_size, void* d_ws, size_t ws_size,
                              hipStream_t stream)
{
    const float* hs   = (const float*)d_in[0];
    const float* mask = (const float*)d_in[1];
    const float* Wq   = (const float*)d_in[2];
    const float* bq   = (const float*)d_in[3];
    const float* Wk   = (const float*)d_in[4];
    const float* bk   = (const float*)d_in[5];
    const float* Wv   = (const float*)d_in[6];
    const float* bv   = (const float*)d_in[7];
    const float* Wo   = (const float*)d_in[8];
    const float* bo   = (const float*)d_in[9];
    // d_in[10] = num_heads (device scalar); shapes are fixed, hardcoded above.

    float* out      = (float*)d_out;
    float* attn_out = out;                              // [B,T,D]
    float* weights  = out + (size_t)BB * TT * DD;       // [B,H,T,T] — also scores scratch

    // Workspace: q | k | v ; ctx aliases q (q is dead after scores). 48 MB total.
    float* q    = (float*)d_ws;
    float* kbuf = q + (size_t)MM * DD;
    float* vbuf = kbuf + (size_t)MM * DD;
    float* ctx  = q;   // reuse

    const dim3 blk(256);

    // QKV projections (scale folded into q)
    gemm_bias_kernel<<<dim3(DD / 64, MM / 128), blk, 0, stream>>>(hs, Wq, bq, q,    MM, DD, DD, SCALING);
    gemm_bias_kernel<<<dim3(DD / 64, MM / 128), blk, 0, stream>>>(hs, Wk, bk, kbuf, MM, DD, DD, 1.0f);
    gemm_bias_kernel<<<dim3(DD / 64, MM / 128), blk, 0, stream>>>(hs, Wv, bv, vbuf, MM, DD, DD, 1.0f);

    // Raw scores (+mask) into attn_weights region
    scores_kernel<<<dim3(TT / 64, TT / 128, BB * HH), blk, 0, stream>>>(q, kbuf, mask, weights);

    // Row softmax in-place
    softmax_kernel<<<dim3(BB * HH * TT), blk, 0, stream>>>(weights);

    // PV: ctx = weights @ v
    pv_kernel<<<dim3(1, TT / 128, BB * HH), blk, 0, stream>>>(weights, vbuf, ctx);

    // Output projection
    gemm_bias_kernel<<<dim3(DD / 64, MM / 128), blk, 0, stream>>>(ctx, Wo, bo, attn_out, MM, DD, DD, 1.0f);
}